// Round 5
// baseline (329.003 us; speedup 1.0000x reference)
//
#include <hip/hip_runtime.h>
#include <stdint.h>

typedef _Float16 h8v __attribute__((ext_vector_type(8)));
typedef float f4v __attribute__((ext_vector_type(4)));
typedef _Float16 f16;

#define NB 8
#define CC 128
#define CB 64
#define NN 4096

// load 8 consecutive fp32, convert to fp16 MFMA fragment (two 16B loads)
__device__ __forceinline__ h8v ld8f(const float* __restrict__ p){
    const f4v a = *(const f4v*)p;
    const f4v b = *(const f4v*)(p + 4);
    h8v r;
    r[0] = (f16)a[0]; r[1] = (f16)a[1]; r[2] = (f16)a[2]; r[3] = (f16)a[3];
    r[4] = (f16)b[0]; r[5] = (f16)b[1]; r[6] = (f16)b[2]; r[7] = (f16)b[3];
    return r;
}

// ---------------------------------------------------------------------------
// Kernel 1: projections (fp32 in -> fp16 intermediates).
// ---------------------------------------------------------------------------
__global__ __launch_bounds__(256) void proj_kernel(
    const float* __restrict__ x, const float* __restrict__ wth,
    const float* __restrict__ wph, const float* __restrict__ wg,
    f16* __restrict__ thetaT, f16* __restrict__ phiT, f16* __restrict__ gbuf)
{
    __shared__ __align__(16) f16 xT[64][136];
    const int b  = blockIdx.x >> 6;
    const int n0 = (blockIdx.x & 63) << 6;
    const int t  = threadIdx.x;

    #pragma unroll
    for (int i = 0; i < 8; i++){
        int v  = t + 256 * i;
        int c  = v >> 4;
        int j0 = (v & 15) << 2;
        const f4v xv = *(const f4v*)&x[((size_t)(b * CC + c)) * NN + n0 + j0];
        #pragma unroll
        for (int jj = 0; jj < 4; jj++) xT[j0 + jj][c] = (f16)xv[jj];
    }
    __syncthreads();

    const int w = t >> 6, lane = t & 63, quad = lane >> 4, l15 = lane & 15;

    h8v a[4];
    #pragma unroll
    for (int kc = 0; kc < 4; kc++)
        a[kc] = *(const h8v*)&xT[w * 16 + l15][kc * 32 + quad * 8];

    #pragma unroll
    for (int m3 = 0; m3 < 2; m3++){
        const float* W = (m3 == 0) ? wth : wph;
        f16* OUT       = (m3 == 0) ? thetaT : phiT;
        for (int ks = 0; ks < 4; ks++){
            f4v acc = {0.f, 0.f, 0.f, 0.f};
            #pragma unroll
            for (int kc = 0; kc < 4; kc++){
                const h8v bf = ld8f(&W[(ks * 16 + l15) * CC + kc * 32 + quad * 8]);
                acc = __builtin_amdgcn_mfma_f32_16x16x32_f16(a[kc], bf, acc, 0, 0, 0);
            }
            #pragma unroll
            for (int r = 0; r < 4; r++){
                int nl = w * 16 + quad * 4 + r;
                int k  = ks * 16 + l15;
                OUT[((size_t)(b * NN + n0 + nl)) * CB + k] = (f16)acc[r];
            }
        }
    }

    h8v aw[4];
    #pragma unroll
    for (int kc = 0; kc < 4; kc++)
        aw[kc] = ld8f(&wg[(w * 16 + l15) * CC + kc * 32 + quad * 8]);
    for (int ns = 0; ns < 4; ns++){
        f4v acc = {0.f, 0.f, 0.f, 0.f};
        #pragma unroll
        for (int kc = 0; kc < 4; kc++){
            const h8v bx = *(const h8v*)&xT[ns * 16 + l15][kc * 32 + quad * 8];
            acc = __builtin_amdgcn_mfma_f32_16x16x32_f16(aw[kc], bx, acc, 0, 0, 0);
        }
        #pragma unroll
        for (int r = 0; r < 4; r++){
            int k = w * 16 + quad * 4 + r;
            int n = n0 + ns * 16 + l15;
            gbuf[((size_t)(b * CB + k)) * NN + n] = (f16)acc[r];
        }
    }
}

// ---------------------------------------------------------------------------
// Kernel 2: flash attention, key-split, 128-key chunks.
// Block = 16 queries; wave w owns 1024 keys as 8 chunks of 128.
// Per-chunk softmax bookkeeping (shuffle-reduce, alpha, rescale) amortized
// over 2x keys vs R4; all global addresses are pointer-increment (no per-iter
// 64-bit index math). Partials merged in LDS.
// ---------------------------------------------------------------------------
__global__ __launch_bounds__(256) void attn_kernel(
    const f16* __restrict__ thetaT, const f16* __restrict__ phiT,
    const f16* __restrict__ gbuf, f16* __restrict__ yT)
{
    __shared__ __align__(16) f16 plds[4][16 * 136];  // per-wave P tile (16 x 128, pad->136)
    __shared__ __align__(16) float oL[4][16][64];    // per-wave partial O
    __shared__ float mwS[4][16], lwS[4][16];

    const int b  = blockIdx.x >> 8;
    const int n0 = (blockIdx.x & 255) << 4;
    const int t  = threadIdx.x;
    const int w = t >> 6, lane = t & 63, quad = lane >> 4, l15 = lane & 15;

    // A-frags (theta^T rows) — same 16 queries for all 4 waves
    const size_t trow = ((size_t)(b * NN + n0 + l15)) * CB;
    const h8v a0 = *(const h8v*)&thetaT[trow + quad * 8];
    const h8v a1 = *(const h8v*)&thetaT[trow + 32 + quad * 8];

    float mrun[4], lrun[4];
    f4v o[4];
    const f4v zf = {0.f, 0.f, 0.f, 0.f};
    #pragma unroll
    for (int r = 0; r < 4; r++){ mrun[r] = -1e30f; lrun[r] = 0.f; }
    #pragma unroll
    for (int tt = 0; tt < 4; tt++) o[tt] = zf;

    const int kbase = w << 10;           // this wave's 1024-key slice
    // pointer-increment bases (advance by 128 keys per chunk)
    const f16* phiP = phiT + ((size_t)(b * NN + kbase + l15)) * CB + quad * 8;
    const f16* gP   = gbuf + ((size_t)(b * CB + l15)) * NN + kbase + quad * 8;
    f16* const pw   = &plds[w][0];

    for (int kb = 0; kb < 8; kb++){
        // ---- S = theta^T phi for 128 keys (8 sub-tiles of 16) ----
        f4v s[8];
        #pragma unroll
        for (int tt = 0; tt < 8; tt++){
            const f16* pr = phiP + (size_t)(tt * 16) * CB;
            const h8v pb0 = *(const h8v*)pr;
            const h8v pb1 = *(const h8v*)(pr + 32);
            f4v sv = zf;
            sv = __builtin_amdgcn_mfma_f32_16x16x32_f16(a0, pb0, sv, 0, 0, 0);
            sv = __builtin_amdgcn_mfma_f32_16x16x32_f16(a1, pb1, sv, 0, 0, 0);
            s[tt] = sv;
        }
        // ---- online softmax over 128 keys: in-lane max over 8 tt, then 4-stage shuffle ----
        float rmax[4];
        #pragma unroll
        for (int r = 0; r < 4; r++){
            float m01 = fmaxf(s[0][r], s[1][r]), m23 = fmaxf(s[2][r], s[3][r]);
            float m45 = fmaxf(s[4][r], s[5][r]), m67 = fmaxf(s[6][r], s[7][r]);
            rmax[r] = fmaxf(fmaxf(m01, m23), fmaxf(m45, m67));
        }
        #pragma unroll
        for (int mask = 1; mask <= 8; mask <<= 1){
            #pragma unroll
            for (int r = 0; r < 4; r++)
                rmax[r] = fmaxf(rmax[r], __shfl_xor(rmax[r], mask));
        }
        float alpha[4];
        #pragma unroll
        for (int r = 0; r < 4; r++){
            float mn = fmaxf(mrun[r], rmax[r]);
            alpha[r] = __expf(mrun[r] - mn);
            mrun[r]  = mn;
            lrun[r] *= alpha[r];
        }
        #pragma unroll
        for (int tt = 0; tt < 8; tt++){
            #pragma unroll
            for (int r = 0; r < 4; r++){
                float p = __expf(s[tt][r] - mrun[r]);
                lrun[r] += p;
                pw[(quad * 4 + r) * 136 + tt * 16 + l15] = (f16)p;
            }
        }
        #pragma unroll
        for (int tt = 0; tt < 4; tt++)
            #pragma unroll
            for (int r = 0; r < 4; r++)
                o[tt][r] *= alpha[r];

        // ---- reload P as A-operand fragments (wave-private LDS) ----
        h8v pa[4];
        #pragma unroll
        for (int kc = 0; kc < 4; kc++)
            pa[kc] = *(const h8v*)&pw[l15 * 136 + kc * 32 + quad * 8];

        // ---- O += P * g^T over 128 keys (4 K-chunks of 32) ----
        #pragma unroll
        for (int tt = 0; tt < 4; tt++){
            const f16* gr = gP + (size_t)(tt * 16) * NN;
            #pragma unroll
            for (int kc = 0; kc < 4; kc++){
                const h8v gb = *(const h8v*)(gr + kc * 32);
                o[tt] = __builtin_amdgcn_mfma_f32_16x16x32_f16(pa[kc], gb, o[tt], 0, 0, 0);
            }
        }
        phiP += (size_t)128 * CB;
        gP   += 128;
    }

    // reduce denominator across the quad's 16 lanes (per-wave partial)
    #pragma unroll
    for (int mask = 1; mask <= 8; mask <<= 1){
        #pragma unroll
        for (int r = 0; r < 4; r++)
            lrun[r] += __shfl_xor(lrun[r], mask);
    }

    // publish per-wave partial state
    #pragma unroll
    for (int tt = 0; tt < 4; tt++)
        #pragma unroll
        for (int r = 0; r < 4; r++)
            oL[w][quad * 4 + r][tt * 16 + l15] = o[tt][r];
    if (l15 == 0){
        #pragma unroll
        for (int r = 0; r < 4; r++){
            mwS[w][quad * 4 + r] = mrun[r];
            lwS[w][quad * 4 + r] = lrun[r];
        }
    }
    __syncthreads();

    // merge 4 partials: thread t -> col = t&63, rows (t>>6)*4 .. +3
    const int col = t & 63;
    #pragma unroll
    for (int rr = 0; rr < 4; rr++){
        const int row = (t >> 6) * 4 + rr;
        const float m0v = mwS[0][row], m1v = mwS[1][row];
        const float m2v = mwS[2][row], m3v = mwS[3][row];
        const float M = fmaxf(fmaxf(m0v, m1v), fmaxf(m2v, m3v));
        const float e0 = __expf(m0v - M), e1 = __expf(m1v - M);
        const float e2 = __expf(m2v - M), e3 = __expf(m3v - M);
        const float L = lwS[0][row] * e0 + lwS[1][row] * e1
                      + lwS[2][row] * e2 + lwS[3][row] * e3;
        const float val = oL[0][row][col] * e0 + oL[1][row][col] * e1
                        + oL[2][row][col] * e2 + oL[3][row][col] * e3;
        yT[((size_t)(b * NN + n0 + row)) * CB + col] = (f16)(val / L);
    }
}

// ---------------------------------------------------------------------------
// Kernel 3: out = w_last * y + x (fp32 out, fp32 residual).
// ---------------------------------------------------------------------------
__global__ __launch_bounds__(256) void out_kernel(
    const float* __restrict__ wl, const f16* __restrict__ yT,
    const float* __restrict__ x, float* __restrict__ out)
{
    const int b  = blockIdx.x >> 6;
    const int n0 = (blockIdx.x & 63) << 6;
    const int t  = threadIdx.x;
    const int w = t >> 6, lane = t & 63, quad = lane >> 4, l15 = lane & 15;

    h8v wlf[2][2];
    #pragma unroll
    for (int cs = 0; cs < 2; cs++)
        #pragma unroll
        for (int kc = 0; kc < 2; kc++)
            wlf[cs][kc] = ld8f(&wl[((w * 2 + cs) * 16 + l15) * CB + kc * 32 + quad * 8]);

    #pragma unroll
    for (int ns = 0; ns < 4; ns++){
        const size_t yrow = ((size_t)(b * NN + n0 + ns * 16 + l15)) * CB;
        const h8v yb0 = *(const h8v*)&yT[yrow + quad * 8];
        const h8v yb1 = *(const h8v*)&yT[yrow + 32 + quad * 8];
        #pragma unroll
        for (int cs = 0; cs < 2; cs++){
            f4v acc = {0.f, 0.f, 0.f, 0.f};
            acc = __builtin_amdgcn_mfma_f32_16x16x32_f16(wlf[cs][0], yb0, acc, 0, 0, 0);
            acc = __builtin_amdgcn_mfma_f32_16x16x32_f16(wlf[cs][1], yb1, acc, 0, 0, 0);
            #pragma unroll
            for (int r = 0; r < 4; r++){
                int c = (w * 2 + cs) * 16 + quad * 4 + r;
                size_t idx = ((size_t)(b * CC + c)) * NN + n0 + ns * 16 + l15;
                out[idx] = acc[r] + x[idx];
            }
        }
    }
}

extern "C" void kernel_launch(void* const* d_in, const int* in_sizes, int n_in,
                              void* d_out, int out_size, void* d_ws, size_t ws_size,
                              hipStream_t stream)
{
    const float* x   = (const float*)d_in[0];
    const float* wth = (const float*)d_in[1];
    const float* wph = (const float*)d_in[2];
    const float* wg  = (const float*)d_in[3];
    const float* wl  = (const float*)d_in[4];
    float* out = (float*)d_out;

    f16* thetaT = (f16*)d_ws;
    f16* phiT   = thetaT + (size_t)NB * NN * CB;
    f16* gbuf   = phiT   + (size_t)NB * NN * CB;
    f16* yT     = gbuf   + (size_t)NB * NN * CB;

    proj_kernel<<<NB * 64, 256, 0, stream>>>(x, wth, wph, wg, thetaT, phiT, gbuf);
    attn_kernel<<<NB * 256, 256, 0, stream>>>(thetaT, phiT, gbuf, yT);
    out_kernel <<<NB * 64, 256, 0, stream>>>(wl, yT, x, out);
}